// Round 13
// baseline (48.685 us; speedup 1.0000x reference)
//
#include <hip/hip_runtime.h>

#define NB 64
#define NT 48
#define NF 128
#define NE 64
#define NCD 32

#define LOG2E 1.4426950408889634f

typedef __attribute__((ext_vector_type(8))) short bf16x8;
typedef __attribute__((ext_vector_type(4))) float f32x4;
typedef __attribute__((ext_vector_type(2))) uint u32x2;

// ---- ws layout (bytes) ----
#define WS_MFLAG 0        // 8192 u32
#define WS_DB    32768    // 8192 u16: bf16(e0-e1)
#define WS_E1B   49152    // bf16(e1)
#define WS_EMB   65536    // bf16(emiss)
#define WS_WLB   81920    // bf16(attn_w * log2e)
#define WS_WT    98304    // [32][128] u16 compress_w^T (upper 64 k-rows E-permuted)
#define WS_BL    106496   // 128 f32 bias*log2e

__device__ __forceinline__ ushort f2bf(float x) {
    union { float f; uint u; } v; v.f = x;
    uint r = v.u + 0x7fffu + ((v.u >> 16) & 1u);   // RNE
    return (ushort)(r >> 16);
}
__device__ __forceinline__ uint pk_bf16(float lo, float hi) {   // v_cvt_pk_bf16_f32
    uint r; asm("v_cvt_pk_bf16_f32 %0, %1, %2" : "=v"(r) : "v"(lo), "v"(hi)); return r;
}
__device__ __forceinline__ float bflo(uint u) { union { uint u; float f; } v; v.u = u << 16; return v.f; }
__device__ __forceinline__ float bfhi(uint u) { union { uint u; float f; } v; v.u = u & 0xffff0000u; return v.f; }

#define TRR(dst, addr, IMM) \
    asm volatile("ds_read_b64_tr_b16 %0, %1 offset:" IMM : "=v"(dst) : "v"(addr))
#define PLSWAP(a, b) asm("v_permlane32_swap_b32 %0, %1" : "+v"(a), "+v"(b))

#define AGG_ISSUE(CR, TB, O0, O1, O2, O3, O4, O5, O6, O7) \
    TRR(CR[0], TB, O0); TRR(CR[1], TB, O1); \
    TRR(CR[2], TB, O2); TRR(CR[3], TB, O3); \
    TRR(CR[4], TB, O4); TRR(CR[5], TB, O5); \
    TRR(CR[6], TB, O6); TRR(CR[7], TB, O7);

// one shared TRR batch feeds BOTH rowgroups: 8 MFMAs
#define AGG_CONSUME2(CR, PFA, PFB, AGA, AGB) { \
    union { u32x2 d[2]; bf16x8 v; } q0, q1, q2, q3; \
    q0.d[0] = CR[0]; q0.d[1] = CR[1]; q1.d[0] = CR[2]; q1.d[1] = CR[3]; \
    q2.d[0] = CR[4]; q2.d[1] = CR[5]; q3.d[0] = CR[6]; q3.d[1] = CR[7]; \
    AGA[0] = __builtin_amdgcn_mfma_f32_16x16x32_bf16(q0.v, PFA, AGA[0], 0, 0, 0); \
    AGB[0] = __builtin_amdgcn_mfma_f32_16x16x32_bf16(q0.v, PFB, AGB[0], 0, 0, 0); \
    AGA[1] = __builtin_amdgcn_mfma_f32_16x16x32_bf16(q1.v, PFA, AGA[1], 0, 0, 0); \
    AGB[1] = __builtin_amdgcn_mfma_f32_16x16x32_bf16(q1.v, PFB, AGB[1], 0, 0, 0); \
    AGA[2] = __builtin_amdgcn_mfma_f32_16x16x32_bf16(q2.v, PFA, AGA[2], 0, 0, 0); \
    AGB[2] = __builtin_amdgcn_mfma_f32_16x16x32_bf16(q2.v, PFB, AGB[2], 0, 0, 0); \
    AGA[3] = __builtin_amdgcn_mfma_f32_16x16x32_bf16(q3.v, PFA, AGA[3], 0, 0, 0); \
    AGB[3] = __builtin_amdgcn_mfma_f32_16x16x32_bf16(q3.v, PFB, AGB[3], 0, 0, 0); }

#define PF_BUILD(PF, PP, KS) { \
    uint X0 = PP[4*(KS)], X1 = PP[4*(KS)+1], X2 = PP[4*(KS)+2], X3 = PP[4*(KS)+3]; \
    PLSWAP(X0, X2); PLSWAP(X1, X3); \
    PF.u[0] = X0; PF.u[1] = X1; PF.u[2] = X2; PF.u[3] = X3; }

#define LGKM_WAIT(N) \
    asm volatile("s_waitcnt lgkmcnt(" #N ")" ::: "memory"); \
    __builtin_amdgcn_sched_barrier(0);

// ---------------- kernel 1: prep ----------------
__global__ __launch_bounds__(256) void prep_kernel(
    const int* __restrict__ mask, const float* __restrict__ e0, const float* __restrict__ e1,
    const float* __restrict__ em, const float* __restrict__ aw, const float* __restrict__ ab,
    const float* __restrict__ cw,
    uint* __restrict__ mflag, ushort* __restrict__ db, ushort* __restrict__ e1b,
    ushort* __restrict__ emb, ushort* __restrict__ wlb, ushort* __restrict__ wt,
    float* __restrict__ bl)
{
    const int blk = blockIdx.x, tid = threadIdx.x;
    if (blk < 32) {                     // tables -> bf16 (+ D = e0-e1, w*log2e)
        int idx = blk * 256 + tid;      // 8192
        float e1v = e1[idx];
        e1b[idx] = f2bf(e1v);
        emb[idx] = f2bf(em[idx]);
        db[idx]  = f2bf(e0[idx] - e1v);
        wlb[idx] = f2bf(aw[idx] * LOG2E);
    } else if (blk < 64) {              // m[b,f] = any_t mask
        int idx = (blk - 32) * 256 + tid;
        int b = idx >> 7, f = idx & 127;
        const int* p = mask + b * (NT * NF) + f;
        int s = 0;
#pragma unroll
        for (int t = 0; t < NT; ++t) s += p[t * NF];
        mflag[idx] = (s != 0) ? 1u : 0u;
    } else if (blk < 80) {              // compress_w -> wt bf16 [32][128], upper half E-permuted
        int idx = (blk - 64) * 256 + tid;
        int k = idx >> 5, d = idx & 31;
        int kd;
        if (k < 64) kd = k;
        else {
            int kk = k - 64;            // E: swap bits 2 and 3 within each 32-group
            kd = 64 + ((kk & 51) | ((kk & 4) << 1) | ((kk & 8) >> 1));
        }
        wt[d * 128 + kd] = f2bf(cw[idx]);
    } else {                            // bias * log2e
        if (tid < NF) bl[tid] = ab[tid] * LOG2E;
    }
}

// ---------------- kernel 2: 8-wave block, wave-halves own one bt each ----------------
// Waves 0-3 -> bt0, waves 4-7 -> bt1; each wave 32 rows (2 rowgroups).
// Shared-C LDS reads (S A-frags read once for 2 rowgroups; TRR batch feeds 8 MFMA)
// halve per-bt LDS traffic (R12 mechanism) at 16 waves/CU (R11 residency).
// LDS: sC[2][9248] u16 = 36992 B. Target 2 blocks/CU.
__global__ __launch_bounds__(512, 4) void fused_kernel(
    const float* __restrict__ input_x, const uint* __restrict__ mflag,
    const ushort* __restrict__ db, const ushort* __restrict__ e1b, const ushort* __restrict__ emb,
    const ushort* __restrict__ wlb, const float* __restrict__ blog,
    const ushort* __restrict__ wt, float* __restrict__ out)
{
    __shared__ ushort sC[2 * 9248];

    const int tid = threadIdx.x;
    const int blk = blockIdx.x;
    const int b   = blk / 24;
    const int ch  = (tid >> 6) >> 2;            // 0: bt0, 1: bt1
    const int bt  = b * NT + (blk % 24) * 2 + ch;

    const int wq = (tid >> 6) & 3, ln = tid & 63;
    const int lr = ln & 15, lg = ln >> 4;
    const int irow0 = wq * 32 + lr;             // rowgroup 0; rowgroup 1 = +16

    ushort* sCm = sC + ch * 9248;

    // per-lane base into sCm (u16 units)
    const int abase = (lg >> 1) * 2312 + (lr >> 2) * 72 + (lr & 3) * 16 + (lg & 1) * 8;

    const float bl0 = blog[irow0];
    const float bl1 = blog[irow0 + 16];

    // ---- phase 1: c for both rowgroups of my bt; CW-frags in regs; C to LDS ----
    bf16x8 cwf[2][2];                   // [g][ks]
#pragma unroll
    for (int g = 0; g < 2; ++g) {
        const int irow = irow0 + g * 16;
        const float x = input_x[bt * NF + irow];
        const ushort* Mrow = (mflag[b * NF + irow] ? e1b : emb) + irow * NE;
        const ushort* Drow = db + irow * NE;
        const ushort* Wrow = wlb + irow * NE;
#pragma unroll
        for (int ks = 0; ks < 2; ++ks) {
            const int eo = ks * 32 + lg * 8;
            uint d4[4], m4[4], w4[4];
            *(uint4*)d4 = *(const uint4*)(Drow + eo);
            *(uint4*)m4 = *(const uint4*)(Mrow + eo);
            *(uint4*)w4 = *(const uint4*)(Wrow + eo);
            uint cb[4]; union { uint u[4]; bf16x8 v; } cu;
#pragma unroll
            for (int j = 0; j < 4; ++j) {
                float clo = fmaf(x, bflo(d4[j]), bflo(m4[j]));
                float chi = fmaf(x, bfhi(d4[j]), bfhi(m4[j]));
                cb[j] = pk_bf16(clo, chi);
                cu.u[j] = pk_bf16(clo * bflo(w4[j]), chi * bfhi(w4[j]));
            }
            cwf[g][ks] = cu.v;
            *(uint4*)&sCm[abase + (wq * 2 + g) * 288 + ks * 4624] = *(uint4*)cb;
        }
    }
    __syncthreads();                    // the ONLY barrier

    // ---- S + SM: A-frags read ONCE, feed both rowgroups (4-tile halves) ----
    uint pp0[16], pp1[16];
    float rsa0[4] = {0.f, 0.f, 0.f, 0.f}, rsa1[4] = {0.f, 0.f, 0.f, 0.f};
#pragma unroll
    for (int half = 0; half < 2; ++half) {
        f32x4 stA[4], stB[4];
#pragma unroll
        for (int j = 0; j < 4; ++j) {
            const int jt = half * 4 + j;
            bf16x8 a0 = *(bf16x8*)&sCm[abase + jt * 288];
            bf16x8 a1 = *(bf16x8*)&sCm[abase + jt * 288 + 4624];
            f32x4 a = (f32x4){bl0, bl0, bl0, bl0};
            a = __builtin_amdgcn_mfma_f32_16x16x32_bf16(a0, cwf[0][0], a, 0, 0, 0);
            a = __builtin_amdgcn_mfma_f32_16x16x32_bf16(a1, cwf[0][1], a, 0, 0, 0);
            stA[j] = a;
            f32x4 c = (f32x4){bl1, bl1, bl1, bl1};
            c = __builtin_amdgcn_mfma_f32_16x16x32_bf16(a0, cwf[1][0], c, 0, 0, 0);
            c = __builtin_amdgcn_mfma_f32_16x16x32_bf16(a1, cwf[1][1], c, 0, 0, 0);
            stB[j] = c;
        }
#pragma unroll
        for (int g = 0; g < 2; ++g) {
            f32x4* st = g ? stB : stA;
            uint* pp = g ? pp1 : pp0;
            float* rsa = g ? rsa1 : rsa0;
            const int dt_ = wq * 2 + g;
#pragma unroll
            for (int j = 0; j < 4; ++j) {
                const int jt = half * 4 + j;
                f32x4 v = st[j];
                float e0 = exp2f(v[0]);
                float e1 = exp2f(v[1]);
                float e2 = exp2f(v[2]);
                float e3 = exp2f(v[3]);
                if (jt == dt_) {        // wave-uniform; diagonal tile
                    const bool on = (lg == (lr >> 2));
                    e0 = (on && (lr & 3) == 0) ? 0.f : e0;
                    e1 = (on && (lr & 3) == 1) ? 0.f : e1;
                    e2 = (on && (lr & 3) == 2) ? 0.f : e2;
                    e3 = (on && (lr & 3) == 3) ? 0.f : e3;
                }
                rsa[0] += e0; rsa[1] += e1; rsa[2] += e2; rsa[3] += e3;
                pp[2 * jt]     = pk_bf16(e0, e1);
                pp[2 * jt + 1] = pk_bf16(e2, e3);
            }
        }
    }
    float rs0 = (rsa0[0] + rsa0[1]) + (rsa0[2] + rsa0[3]);
    rs0 += __shfl_xor(rs0, 16);
    rs0 += __shfl_xor(rs0, 32);
    const float inv0 = 1.0f / (rs0 + 1e-8f);
    float rs1 = (rsa1[0] + rsa1[1]) + (rsa1[2] + rsa1[3]);
    rs1 += __shfl_xor(rs1, 16);
    rs1 += __shfl_xor(rs1, 32);
    const float inv1 = 1.0f / (rs1 + 1e-8f);

    // ---- AGG^T: shared TRR batches (2-deep counted-lgkm), 8 MFMA per batch ----
    f32x4 agA[4], agB[4];
#pragma unroll
    for (int et = 0; et < 4; ++et) { agA[et] = (f32x4){0.f,0.f,0.f,0.f}; agB[et] = (f32x4){0.f,0.f,0.f,0.f}; }
    {
        const uint tb = (uint)(uintptr_t)sCm
                      + 2u * (uint)(72 * (((lg >> 1) << 2) + (lg & 1)) + lr);
        u32x2 cA[8], cB[8];
        union { uint u[4]; bf16x8 v; } pfA0, pfB0, pfA1, pfB1, pfA2, pfB2, pfA3, pfB3;
        PF_BUILD(pfA0, pp0, 0); PF_BUILD(pfB0, pp1, 0);
        AGG_ISSUE(cA, tb, "0", "144", "4624", "4768", "9248", "9392", "13872", "14016");
        PF_BUILD(pfA1, pp0, 1); PF_BUILD(pfB1, pp1, 1);
        AGG_ISSUE(cB, tb, "1152", "1296", "5776", "5920", "10400", "10544", "15024", "15168");
        LGKM_WAIT(8);                   // batch 0 done (pure-DS, in-order)
        AGG_CONSUME2(cA, pfA0.v, pfB0.v, agA, agB);
        PF_BUILD(pfA2, pp0, 2); PF_BUILD(pfB2, pp1, 2);
        AGG_ISSUE(cA, tb, "2304", "2448", "6928", "7072", "11552", "11696", "16176", "16320");
        LGKM_WAIT(8);                   // batch 1 done
        AGG_CONSUME2(cB, pfA1.v, pfB1.v, agA, agB);
        PF_BUILD(pfA3, pp0, 3); PF_BUILD(pfB3, pp1, 3);
        AGG_ISSUE(cB, tb, "3456", "3600", "8080", "8224", "12704", "12848", "17328", "17472");
        LGKM_WAIT(8);                   // batch 2 done
        AGG_CONSUME2(cA, pfA2.v, pfB2.v, agA, agB);
        LGKM_WAIT(0);                   // batch 3 done
        AGG_CONSUME2(cB, pfA3.v, pfB3.v, agA, agB);
    }

    // ---- EPI per rowgroup: normalize, .*C, relu -> packed aa ----
    uint aa0[8], aa1[8];
#pragma unroll
    for (int g = 0; g < 2; ++g) {
        const f32x4* ag = g ? agB : agA;
        const float inv = g ? inv1 : inv0;
        uint* aa = g ? aa1 : aa0;
        const int ebase = (wq * 8 + g * 4 + (lr >> 2)) * 72 + (lr & 3) * 16 + lg * 4;
#pragma unroll
        for (int et = 0; et < 4; ++et) {
            u32x2 cb2 = *(u32x2*)&sCm[ebase + et * 2312];
            float a0f = fmaxf(ag[et][0] * inv * bflo(cb2.x), 0.f);
            float a1f = fmaxf(ag[et][1] * inv * bfhi(cb2.x), 0.f);
            float a2f = fmaxf(ag[et][2] * inv * bflo(cb2.y), 0.f);
            float a3f = fmaxf(ag[et][3] * inv * bfhi(cb2.y), 0.f);
            aa[2 * et]     = pk_bf16(a0f, a1f);
            aa[2 * et + 1] = pk_bf16(a2f, a3f);
        }
    }

    // ---- OUT: fused ks-loop, one wf load set feeds both rowgroups ----
    f32x4 ocA[2], ocB[2];
    ocA[0] = (f32x4){0.f,0.f,0.f,0.f}; ocA[1] = (f32x4){0.f,0.f,0.f,0.f};
    ocB[0] = (f32x4){0.f,0.f,0.f,0.f}; ocB[1] = (f32x4){0.f,0.f,0.f,0.f};
#pragma unroll
    for (int ks = 0; ks < 4; ++ks) {
        bf16x8 wf0 = *(const bf16x8*)(wt + lr * 128 + ks * 32 + lg * 8);
        bf16x8 wf1 = *(const bf16x8*)(wt + (16 + lr) * 128 + ks * 32 + lg * 8);
        bf16x8 afrA, afrB;
        if (ks < 2) {
            const uint4 ccA = *(uint4*)&sCm[abase + (wq * 2 + 0) * 288 + ks * 4624];
            const uint4 ccB = *(uint4*)&sCm[abase + (wq * 2 + 1) * 288 + ks * 4624];
            union { uint u[4]; bf16x8 v; } rA, rB;
            asm("v_pk_max_i16 %0, %1, 0" : "=v"(rA.u[0]) : "v"(ccA.x));
            asm("v_pk_max_i16 %0, %1, 0" : "=v"(rA.u[1]) : "v"(ccA.y));
            asm("v_pk_max_i16 %0, %1, 0" : "=v"(rA.u[2]) : "v"(ccA.z));
            asm("v_pk_max_i16 %0, %1, 0" : "=v"(rA.u[3]) : "v"(ccA.w));
            asm("v_pk_max_i16 %0, %1, 0" : "=v"(rB.u[0]) : "v"(ccB.x));
            asm("v_pk_max_i16 %0, %1, 0" : "=v"(rB.u[1]) : "v"(ccB.y));
            asm("v_pk_max_i16 %0, %1, 0" : "=v"(rB.u[2]) : "v"(ccB.z));
            asm("v_pk_max_i16 %0, %1, 0" : "=v"(rB.u[3]) : "v"(ccB.w));
            afrA = rA.v; afrB = rB.v;
        } else {
            const int kk = ks - 2;
            uint YA0 = aa0[4*kk], YA1 = aa0[4*kk+1], YA2 = aa0[4*kk+2], YA3 = aa0[4*kk+3];
            PLSWAP(YA0, YA2); PLSWAP(YA1, YA3);
            uint YB0 = aa1[4*kk], YB1 = aa1[4*kk+1], YB2 = aa1[4*kk+2], YB3 = aa1[4*kk+3];
            PLSWAP(YB0, YB2); PLSWAP(YB1, YB3);
            union { uint u[4]; bf16x8 v; } fA, fB;
            fA.u[0] = YA0; fA.u[1] = YA1; fA.u[2] = YA2; fA.u[3] = YA3;
            fB.u[0] = YB0; fB.u[1] = YB1; fB.u[2] = YB2; fB.u[3] = YB3;
            afrA = fA.v; afrB = fB.v;
        }
        ocA[0] = __builtin_amdgcn_mfma_f32_16x16x32_bf16(afrA, wf0, ocA[0], 0, 0, 0);
        ocA[1] = __builtin_amdgcn_mfma_f32_16x16x32_bf16(afrA, wf1, ocA[1], 0, 0, 0);
        ocB[0] = __builtin_amdgcn_mfma_f32_16x16x32_bf16(afrB, wf0, ocB[0], 0, 0, 0);
        ocB[1] = __builtin_amdgcn_mfma_f32_16x16x32_bf16(afrB, wf1, ocB[1], 0, 0, 0);
    }
    float* op = out + bt * (NF * NCD);
#pragma unroll
    for (int dt = 0; dt < 2; ++dt)
#pragma unroll
        for (int r = 0; r < 4; ++r) {
            op[(wq * 32 + lg * 4 + r) * NCD + dt * 16 + lr]      = ocA[dt][r];
            op[(wq * 32 + 16 + lg * 4 + r) * NCD + dt * 16 + lr] = ocB[dt][r];
        }
}

extern "C" void kernel_launch(void* const* d_in, const int* in_sizes, int n_in,
                              void* d_out, int out_size, void* d_ws, size_t ws_size,
                              hipStream_t stream) {
    const float* input_x       = (const float*)d_in[0];
    const int*   mask          = (const int*)d_in[1];
    const float* embed0        = (const float*)d_in[2];
    const float* embed1        = (const float*)d_in[3];
    const float* embed_missing = (const float*)d_in[4];
    const float* attn_w        = (const float*)d_in[5];
    const float* attn_b        = (const float*)d_in[6];
    const float* compress_w    = (const float*)d_in[7];
    float* out = (float*)d_out;

    char* ws = (char*)d_ws;
    uint*   mflag = (uint*)(ws + WS_MFLAG);
    ushort* dbp   = (ushort*)(ws + WS_DB);
    ushort* e1bp  = (ushort*)(ws + WS_E1B);
    ushort* embp  = (ushort*)(ws + WS_EMB);
    ushort* wlbp  = (ushort*)(ws + WS_WLB);
    ushort* wtp   = (ushort*)(ws + WS_WT);
    float*  blp   = (float*)(ws + WS_BL);

    hipLaunchKernelGGL(prep_kernel, dim3(81), dim3(256), 0, stream,
                       mask, embed0, embed1, embed_missing, attn_w, attn_b, compress_w,
                       mflag, dbp, e1bp, embp, wlbp, wtp, blp);
    hipLaunchKernelGGL(fused_kernel, dim3(NB * NT / 2), dim3(512), 0, stream,
                       input_x, mflag, dbp, e1bp, embp, wlbp, blp, wtp, out);
}

// Round 15
// 39.307 us; speedup vs baseline: 1.2386x; 1.2386x over previous
//
#include <hip/hip_runtime.h>

#define NB 64
#define NT 48
#define NF 128
#define NE 64
#define NCD 32

#define LOG2E 1.4426950408889634f

typedef __attribute__((ext_vector_type(8))) short bf16x8;
typedef __attribute__((ext_vector_type(4))) float f32x4;
typedef __attribute__((ext_vector_type(2))) uint u32x2;

// ---- ws layout (bytes) ----
#define WS_MFLAG 0        // 8192 u32
#define WS_DB    32768    // 8192 u16: bf16(e0-e1)
#define WS_E1B   49152    // bf16(e1)
#define WS_EMB   65536    // bf16(emiss)
#define WS_WLB   81920    // bf16(attn_w * log2e)
#define WS_WT    98304    // [32][128] u16 compress_w^T (upper 64 k-rows E-permuted)
#define WS_BL    106496   // 128 f32 bias*log2e

__device__ __forceinline__ ushort f2bf(float x) {
    union { float f; uint u; } v; v.f = x;
    uint r = v.u + 0x7fffu + ((v.u >> 16) & 1u);   // RNE
    return (ushort)(r >> 16);
}
__device__ __forceinline__ uint pk_bf16(float lo, float hi) {   // v_cvt_pk_bf16_f32
    uint r; asm("v_cvt_pk_bf16_f32 %0, %1, %2" : "=v"(r) : "v"(lo), "v"(hi)); return r;
}
__device__ __forceinline__ float bflo(uint u) { union { uint u; float f; } v; v.u = u << 16; return v.f; }
__device__ __forceinline__ float bfhi(uint u) { union { uint u; float f; } v; v.u = u & 0xffff0000u; return v.f; }
// raw HW transcendentals (inputs bounded: |arg|<~2 -> no denormal/edge handling needed)
__device__ __forceinline__ float exp2i(float x) { float r; asm("v_exp_f32 %0, %1" : "=v"(r) : "v"(x)); return r; }
__device__ __forceinline__ float rcpi(float x)  { float r; asm("v_rcp_f32 %0, %1" : "=v"(r) : "v"(x)); return r; }

#define TRR(dst, addr, IMM) \
    asm volatile("ds_read_b64_tr_b16 %0, %1 offset:" IMM : "=v"(dst) : "v"(addr))
#define PLSWAP(a, b) asm("v_permlane32_swap_b32 %0, %1" : "+v"(a), "+v"(b))

// issue one 8-TRR batch; trailing sched_barrier(0) pins the gap to the
// following LGKM_WAIT so the compiler cannot insert s_loads (SMEM completes
// OUT-OF-ORDER on lgkmcnt -> counted DS waits are only sound in SMEM-free windows)
#define AGG_ISSUE(CR, TB, O0, O1, O2, O3, O4, O5, O6, O7) \
    TRR(CR[0], TB, O0); TRR(CR[1], TB, O1); \
    TRR(CR[2], TB, O2); TRR(CR[3], TB, O3); \
    TRR(CR[4], TB, O4); TRR(CR[5], TB, O5); \
    TRR(CR[6], TB, O6); TRR(CR[7], TB, O7); \
    __builtin_amdgcn_sched_barrier(0);

#define AGG_CONSUME(CR, PF, AG) { \
    union { u32x2 d[2]; bf16x8 v; } q0, q1, q2, q3; \
    q0.d[0] = CR[0]; q0.d[1] = CR[1]; q1.d[0] = CR[2]; q1.d[1] = CR[3]; \
    q2.d[0] = CR[4]; q2.d[1] = CR[5]; q3.d[0] = CR[6]; q3.d[1] = CR[7]; \
    AG[0] = __builtin_amdgcn_mfma_f32_16x16x32_bf16(q0.v, PF, AG[0], 0, 0, 0); \
    AG[1] = __builtin_amdgcn_mfma_f32_16x16x32_bf16(q1.v, PF, AG[1], 0, 0, 0); \
    AG[2] = __builtin_amdgcn_mfma_f32_16x16x32_bf16(q2.v, PF, AG[2], 0, 0, 0); \
    AG[3] = __builtin_amdgcn_mfma_f32_16x16x32_bf16(q3.v, PF, AG[3], 0, 0, 0); }

#define PF_BUILD(PF, PP, KS) { \
    uint X0 = PP[4*(KS)], X1 = PP[4*(KS)+1], X2 = PP[4*(KS)+2], X3 = PP[4*(KS)+3]; \
    PLSWAP(X0, X2); PLSWAP(X1, X3); \
    PF.u[0] = X0; PF.u[1] = X1; PF.u[2] = X2; PF.u[3] = X3; }

#define LGKM_WAIT(N) \
    asm volatile("s_waitcnt lgkmcnt(" #N ")" ::: "memory"); \
    __builtin_amdgcn_sched_barrier(0);

// ---------------- kernel 1: prep ----------------
__global__ __launch_bounds__(256) void prep_kernel(
    const int* __restrict__ mask, const float* __restrict__ e0, const float* __restrict__ e1,
    const float* __restrict__ em, const float* __restrict__ aw, const float* __restrict__ ab,
    const float* __restrict__ cw,
    uint* __restrict__ mflag, ushort* __restrict__ db, ushort* __restrict__ e1b,
    ushort* __restrict__ emb, ushort* __restrict__ wlb, ushort* __restrict__ wt,
    float* __restrict__ bl)
{
    const int blk = blockIdx.x, tid = threadIdx.x;
    if (blk < 32) {                     // tables -> bf16 (+ D = e0-e1, w*log2e)
        int idx = blk * 256 + tid;      // 8192
        float e1v = e1[idx];
        e1b[idx] = f2bf(e1v);
        emb[idx] = f2bf(em[idx]);
        db[idx]  = f2bf(e0[idx] - e1v);
        wlb[idx] = f2bf(aw[idx] * LOG2E);
    } else if (blk < 64) {              // m[b,f] = any_t mask
        int idx = (blk - 32) * 256 + tid;
        int b = idx >> 7, f = idx & 127;
        const int* p = mask + b * (NT * NF) + f;
        int s = 0;
#pragma unroll
        for (int t = 0; t < NT; ++t) s += p[t * NF];
        mflag[idx] = (s != 0) ? 1u : 0u;
    } else if (blk < 80) {              // compress_w -> wt bf16 [32][128], upper half E-permuted
        int idx = (blk - 64) * 256 + tid;
        int k = idx >> 5, d = idx & 31;
        int kd;
        if (k < 64) kd = k;
        else {
            int kk = k - 64;            // E: swap bits 2 and 3 within each 32-group
            kd = 64 + ((kk & 51) | ((kk & 4) << 1) | ((kk & 8) >> 1));
        }
        wt[d * 128 + kd] = f2bf(cw[idx]);
    } else {                            // bias * log2e
        if (tid < NF) bl[tid] = ab[tid] * LOG2E;
    }
}

// ---------------- kernel 2: dual-(b,t) pipeline (R11 structure, hardened waits) ----------------
// LDS: sC[2][9248] u16 = 36992 B. 16 waves/CU.
__global__ __launch_bounds__(512, 4) void fused_kernel(
    const float* __restrict__ input_x, const uint* __restrict__ mflag,
    const ushort* __restrict__ db, const ushort* __restrict__ e1b, const ushort* __restrict__ emb,
    const ushort* __restrict__ wlb, const float* __restrict__ blog,
    const ushort* __restrict__ wt, float* __restrict__ out)
{
    __shared__ ushort sC[2 * 9248];

    const int tid = threadIdx.x;
    const int blk = blockIdx.x;
    const int b   = blk / 24;
    const int bt0 = b * NT + (blk % 24) * 2;
    const int bt1 = bt0 + 1;

    const int wv = tid >> 6, ln = tid & 63;
    const int lr = ln & 15, lg = ln >> 4;
    const int i0 = wv << 4, irow = i0 + lr;

    const float bl = blog[irow];
    const float x0 = input_x[bt0 * NF + irow];
    const float x1 = input_x[bt1 * NF + irow];
    const ushort* Mrow = (mflag[b * NF + irow] ? e1b : emb) + irow * NE;
    const ushort* Drow = db + irow * NE;
    const ushort* Wrow = wlb + irow * NE;

    const int sbase = (lg >> 1) * 2312 + (lr >> 2) * 72 + (lr & 3) * 16 + (lg & 1) * 8;

    ushort* sC0 = sC;
    ushort* sC1 = sC + 9248;

    // ---- phase 1: unpack D/M/W once; c(t0), c(t1) to LDS; CW-frags in regs ----
    bf16x8 cwf0[2], cwf1[2];
#pragma unroll
    for (int ks = 0; ks < 2; ++ks) {
        const int eo = ks * 32 + lg * 8;
        uint d4[4], m4[4], w4[4];
        *(uint4*)d4 = *(const uint4*)(Drow + eo);
        *(uint4*)m4 = *(const uint4*)(Mrow + eo);
        *(uint4*)w4 = *(const uint4*)(Wrow + eo);
        uint cb0[4], cb1[4];
        union { uint u[4]; bf16x8 v; } cw0, cw1;
#pragma unroll
        for (int j = 0; j < 4; ++j) {
            float dlo = bflo(d4[j]), dhi = bfhi(d4[j]);
            float mlo = bflo(m4[j]), mhi = bfhi(m4[j]);
            float wlo = bflo(w4[j]), whi = bfhi(w4[j]);
            float c0lo = fmaf(x0, dlo, mlo), c0hi = fmaf(x0, dhi, mhi);
            float c1lo = fmaf(x1, dlo, mlo), c1hi = fmaf(x1, dhi, mhi);
            cb0[j] = pk_bf16(c0lo, c0hi);
            cb1[j] = pk_bf16(c1lo, c1hi);
            cw0.u[j] = pk_bf16(c0lo * wlo, c0hi * whi);
            cw1.u[j] = pk_bf16(c1lo * wlo, c1hi * whi);
        }
        cwf0[ks] = cw0.v; cwf1[ks] = cw1.v;
        *(uint4*)&sC0[sbase + wv * 288 + ks * 4624] = *(uint4*)cb0;
        *(uint4*)&sC1[sbase + wv * 288 + ks * 4624] = *(uint4*)cb1;
    }
    __syncthreads();                    // the ONLY barrier

    // ================= helpers =================
    auto run_S4 = [&](const ushort* base, bf16x8 w0, bf16x8 w1, int jt0, f32x4* st4) {
#pragma unroll
        for (int j = 0; j < 4; ++j) {
            const int jt = jt0 + j;
            f32x4 a = (f32x4){bl, bl, bl, bl};
            bf16x8 a0 = *(bf16x8*)&base[sbase + jt * 288];
            a = __builtin_amdgcn_mfma_f32_16x16x32_bf16(a0, w0, a, 0, 0, 0);
            bf16x8 a1 = *(bf16x8*)&base[sbase + jt * 288 + 4624];
            a = __builtin_amdgcn_mfma_f32_16x16x32_bf16(a1, w1, a, 0, 0, 0);
            st4[j] = a;
        }
    };
    auto run_SM4 = [&](f32x4* st4, uint* pp, int jt0, float* rsa) {
#pragma unroll
        for (int j = 0; j < 4; ++j) {
            const int jt = jt0 + j;
            f32x4 v = st4[j];
            float e0 = exp2i(v[0]);
            float e1 = exp2i(v[1]);
            float e2 = exp2i(v[2]);
            float e3 = exp2i(v[3]);
            if (jt == wv) {             // wave-uniform; diagonal lives in tile jt==wv
                const bool on = (lg == (lr >> 2));
                e0 = (on && (lr & 3) == 0) ? 0.f : e0;
                e1 = (on && (lr & 3) == 1) ? 0.f : e1;
                e2 = (on && (lr & 3) == 2) ? 0.f : e2;
                e3 = (on && (lr & 3) == 3) ? 0.f : e3;
            }
            rsa[0] += e0; rsa[1] += e1; rsa[2] += e2; rsa[3] += e3;
            pp[2 * jt]     = pk_bf16(e0, e1);
            pp[2 * jt + 1] = pk_bf16(e2, e3);
        }
    };
    auto run_chainS = [&](const ushort* base, bf16x8 w0, bf16x8 w1, uint* pp) -> float {
        f32x4 st4[4];
        float rsa[4] = {0.f, 0.f, 0.f, 0.f};
        run_S4(base, w0, w1, 0, st4);
        run_SM4(st4, pp, 0, rsa);
        run_S4(base, w0, w1, 4, st4);
        run_SM4(st4, pp, 4, rsa);
        float rs = (rsa[0] + rsa[1]) + (rsa[2] + rsa[3]);
        rs += __shfl_xor(rs, 16);
        rs += __shfl_xor(rs, 32);
        return rcpi(rs + 1e-8f);
    };
    // AGG^T: 2 TRR batches in flight, counted lgkm waits.
    // Entry drain (lgkmcnt(0)) clears any outstanding SMEM; sched_barrier after
    // each issue keeps the issue->wait windows SMEM-free (counted-wait soundness).
    auto run_AGG = [&](const ushort* base, uint* pp, f32x4* ag) {
#pragma unroll
        for (int et = 0; et < 4; ++et) ag[et] = (f32x4){0.f, 0.f, 0.f, 0.f};
        const uint tb = (uint)(uintptr_t)base
                      + 2u * (uint)(72 * (((lg >> 1) << 2) + (lg & 1)) + lr);
        u32x2 cA[8], cB[8];
        union { uint u[4]; bf16x8 v; } pf0, pf1, pf2, pf3;
        LGKM_WAIT(0);                   // entry drain: no SMEM/DS outstanding
        PF_BUILD(pf0, pp, 0);
        AGG_ISSUE(cA, tb, "0", "144", "4624", "4768", "9248", "9392", "13872", "14016");
        PF_BUILD(pf1, pp, 1);
        AGG_ISSUE(cB, tb, "1152", "1296", "5776", "5920", "10400", "10544", "15024", "15168");
        LGKM_WAIT(8);                   // batch 0 done (DS in-order, window SMEM-free)
        AGG_CONSUME(cA, pf0.v, ag);
        PF_BUILD(pf2, pp, 2);
        AGG_ISSUE(cA, tb, "2304", "2448", "6928", "7072", "11552", "11696", "16176", "16320");
        LGKM_WAIT(8);                   // batch 1 done
        AGG_CONSUME(cB, pf1.v, ag);
        PF_BUILD(pf3, pp, 3);
        AGG_ISSUE(cB, tb, "3456", "3600", "8080", "8224", "12704", "12848", "17328", "17472");
        LGKM_WAIT(8);                   // batch 2 done
        AGG_CONSUME(cA, pf2.v, ag);
        LGKM_WAIT(0);                   // batch 3 done
        AGG_CONSUME(cB, pf3.v, ag);
    };
    auto run_EPI = [&](const ushort* base, f32x4* ag, float inv, uint* aa) {
        const int ebase = (wv * 4 + (lr >> 2)) * 72 + (lr & 3) * 16 + lg * 4;
#pragma unroll
        for (int et = 0; et < 4; ++et) {
            u32x2 cb2 = *(u32x2*)&base[ebase + et * 2312];
            float a0f = fmaxf(ag[et][0] * inv * bflo(cb2.x), 0.f);
            float a1f = fmaxf(ag[et][1] * inv * bfhi(cb2.x), 0.f);
            float a2f = fmaxf(ag[et][2] * inv * bflo(cb2.y), 0.f);
            float a3f = fmaxf(ag[et][3] * inv * bfhi(cb2.y), 0.f);
            aa[2 * et]     = pk_bf16(a0f, a1f);
            aa[2 * et + 1] = pk_bf16(a2f, a3f);
        }
    };
    auto run_OUT = [&](const ushort* base, uint* aa, const bf16x8* wf, int bt) {
        f32x4 oc[2];
        oc[0] = (f32x4){0.f, 0.f, 0.f, 0.f};
        oc[1] = (f32x4){0.f, 0.f, 0.f, 0.f};
#pragma unroll
        for (int ks = 0; ks < 4; ++ks) {
            bf16x8 afr;
            if (ks < 2) {
                const uint4 cc = *(uint4*)&base[sbase + wv * 288 + ks * 4624];
                union { uint u[4]; bf16x8 v; } rl;
                asm("v_pk_max_i16 %0, %1, 0" : "=v"(rl.u[0]) : "v"(cc.x));
                asm("v_pk_max_i16 %0, %1, 0" : "=v"(rl.u[1]) : "v"(cc.y));
                asm("v_pk_max_i16 %0, %1, 0" : "=v"(rl.u[2]) : "v"(cc.z));
                asm("v_pk_max_i16 %0, %1, 0" : "=v"(rl.u[3]) : "v"(cc.w));
                afr = rl.v;
            } else {
                const int kk = ks - 2;
                uint Y0 = aa[4 * kk], Y1 = aa[4 * kk + 1], Y2 = aa[4 * kk + 2], Y3 = aa[4 * kk + 3];
                PLSWAP(Y0, Y2);
                PLSWAP(Y1, Y3);
                union { uint u[4]; bf16x8 v; } af;
                af.u[0] = Y0; af.u[1] = Y1; af.u[2] = Y2; af.u[3] = Y3;
                afr = af.v;
            }
            oc[0] = __builtin_amdgcn_mfma_f32_16x16x32_bf16(afr, wf[ks * 2 + 0], oc[0], 0, 0, 0);
            oc[1] = __builtin_amdgcn_mfma_f32_16x16x32_bf16(afr, wf[ks * 2 + 1], oc[1], 0, 0, 0);
        }
        float* op = out + bt * (NF * NCD);
#pragma unroll
        for (int dt = 0; dt < 2; ++dt)
#pragma unroll
            for (int r = 0; r < 4; ++r)
                op[(i0 + lg * 4 + r) * NCD + dt * 16 + lr] = oc[dt][r];
    };

    // ================= staggered dual-chain schedule (R11 order) =================
    uint pp0[16], pp1[16];
    f32x4 ag0[4], ag1[4];
    uint aa0[8], aa1[8];

    const float inv0 = run_chainS(sC0, cwf0[0], cwf0[1], pp0);
    const float inv1 = run_chainS(sC1, cwf1[0], cwf1[1], pp1);

    run_AGG(sC0, pp0, ag0);                     // pp0 dead
    run_EPI(sC0, ag0, inv0, aa0);               // ag0 dead
    run_AGG(sC1, pp1, ag1);                     // pp1 dead

    bf16x8 wf[8];                               // Wt B-frags (shared by both chains)
#pragma unroll
    for (int ks = 0; ks < 4; ++ks)
#pragma unroll
        for (int dt = 0; dt < 2; ++dt)
            wf[ks * 2 + dt] = *(const bf16x8*)(wt + (dt * 16 + lr) * 128 + ks * 32 + lg * 8);

    run_EPI(sC1, ag1, inv1, aa1);               // ag1 dead
    run_OUT(sC0, aa0, wf, bt0);
    run_OUT(sC1, aa1, wf, bt1);
}

extern "C" void kernel_launch(void* const* d_in, const int* in_sizes, int n_in,
                              void* d_out, int out_size, void* d_ws, size_t ws_size,
                              hipStream_t stream) {
    const float* input_x       = (const float*)d_in[0];
    const int*   mask          = (const int*)d_in[1];
    const float* embed0        = (const float*)d_in[2];
    const float* embed1        = (const float*)d_in[3];
    const float* embed_missing = (const float*)d_in[4];
    const float* attn_w        = (const float*)d_in[5];
    const float* attn_b        = (const float*)d_in[6];
    const float* compress_w    = (const float*)d_in[7];
    float* out = (float*)d_out;

    char* ws = (char*)d_ws;
    uint*   mflag = (uint*)(ws + WS_MFLAG);
    ushort* dbp   = (ushort*)(ws + WS_DB);
    ushort* e1bp  = (ushort*)(ws + WS_E1B);
    ushort* embp  = (ushort*)(ws + WS_EMB);
    ushort* wlbp  = (ushort*)(ws + WS_WLB);
    ushort* wtp   = (ushort*)(ws + WS_WT);
    float*  blp   = (float*)(ws + WS_BL);

    hipLaunchKernelGGL(prep_kernel, dim3(81), dim3(256), 0, stream,
                       mask, embed0, embed1, embed_missing, attn_w, attn_b, compress_w,
                       mflag, dbp, e1bp, embp, wlbp, wtp, blp);
    hipLaunchKernelGGL(fused_kernel, dim3(NB * NT / 2), dim3(512), 0, stream,
                       input_x, mflag, dbp, e1bp, embp, wlbp, blp, wtp, out);
}